// Round 5
// baseline (365.891 us; speedup 1.0000x reference)
//
#include <hip/hip_runtime.h>

#define N_NODES 100000
#define E_EDGES 800000
#define IN_F 256
#define D_HEAD 64
#define H_HEADS 4
#define EF_F 64
#define NET_T 8
#define HD 256          // H*D
#define SLOPE 0.2f
#define NTILES ((N_NODES + 63) / 64)

typedef unsigned short u16;
typedef unsigned long long u64;
typedef __attribute__((ext_vector_type(8))) short bf16x8;
typedef __attribute__((ext_vector_type(4))) float f32x4;

static __device__ __forceinline__ u16 f2bf(float f) {
    unsigned int u = __float_as_uint(f);
    unsigned int r = u + 0x7FFFu + ((u >> 16) & 1u);
    return (u16)(r >> 16);
}
static __device__ __forceinline__ float bf2f(unsigned int u) {
    return __uint_as_float(u << 16);
}

// ---------------- K0: s_e[t][h] = sum_f a_e[h,f] * (edge_emb @ W_e)[t,h,f] ----------------
__global__ void k_se(const float* __restrict__ edge_emb, const float* __restrict__ W_e,
                     const float* __restrict__ a_e, float* __restrict__ s_e) {
    int tid = threadIdx.x;           // 256 threads
    int t  = tid >> 5;               // 0..7
    int h  = (tid >> 3) & 3;         // 0..3
    int fc = tid & 7;                // 0..7
    float part = 0.f;
    for (int j = 0; j < 8; ++j) {
        int f = fc * 8 + j;
        float acc = 0.f;
        for (int k = 0; k < EF_F; ++k)
            acc += edge_emb[t * EF_F + k] * W_e[k * (EF_F * H_HEADS) + h * EF_F + f];
        part += a_e[h * EF_F + f] * acc;
    }
    for (int off = 1; off < 8; off <<= 1)
        part += __shfl_xor(part, off, 64);
    if (fc == 0) s_e[t * H_HEADS + h] = part;
}

// ---------------- K1: Bfrag[g][ks][n][lane] fragment-major bf16 of [W | res_W]^T ----------
__global__ void k_prep_w(const float* __restrict__ W, const float* __restrict__ resW,
                         u16* __restrict__ Bfrag) {
    const int gid = blockIdx.x * 256 + threadIdx.x;   // 16384 total
    const int lane = gid & 63;
    const int fragid = gid >> 6;          // 0..255 = g*32 + ks*4 + n
    const int n = fragid & 3;
    const int ks = (fragid >> 2) & 7;
    const int g = fragid >> 5;            // 0..7
    const int c = g * 64 + n * 16 + (lane & 15);      // 0..511
    const int k0 = ks * 32 + (lane >> 4) * 8;
    const float* src = (c < HD) ? &W[c] : &resW[c - HD];
    u16 tmp[8];
#pragma unroll
    for (int j = 0; j < 8; ++j)
        tmp[j] = f2bf(src[(size_t)(k0 + j) * HD]);
    *reinterpret_cast<uint4*>(&Bfrag[(size_t)fragid * 512 + lane * 8]) =
        *reinterpret_cast<const uint4*>(tmp);
}

// ---------------- K2: persistent-B MFMA GEMM (grid-stride tiles) --------------------------
// 512 thr = 8 waves. Each wave hoists its 32 B fragments (128 VGPR) ONCE, then
// grid-strides over 64-row tiles: stage A->LDS (fp32->bf16, XOR-swizzled), pure
// LDS+MFMA k-loop, fused epilogue. No global loads inside the k-loop.
__global__ __launch_bounds__(512, 1)
void k_mfma(const float* __restrict__ A, const u16* __restrict__ Bfrag,
            const float* __restrict__ a_l, const float* __restrict__ a_r,
            const float* __restrict__ resb,
            u16* __restrict__ emb_bf, float* __restrict__ s_l, float* __restrict__ s_r,
            float* __restrict__ outp) {
    __shared__ char At[32768];       // 64 rows x 256 bf16, XOR-swizzled
    const int tid = threadIdx.x;
    const int lane = tid & 63;
    const int wid = tid >> 6;        // 0..7 = channel-group
    const int lr = lane & 15;
    const int lg = lane >> 4;
    const int xr = (lr & 7) << 4;
    const int klg = lg * 16;

    // ---- hoist all B fragments into registers (persistent across tiles) ----
    const u16* bp = Bfrag + (size_t)wid * 16384 + lane * 8;
    bf16x8 bfr[8][4];
#pragma unroll
    for (int ks = 0; ks < 8; ++ks)
#pragma unroll
        for (int n = 0; n < 4; ++n)
            bfr[ks][n] = *reinterpret_cast<const bf16x8*>(&bp[ks * 2048 + n * 512]);

    int rowbase[4];
#pragma unroll
    for (int m = 0; m < 4; ++m) rowbase[m] = (m * 16 + lr) * 512;

    for (int tile = blockIdx.x; tile < NTILES; tile += gridDim.x) {
        const int row0 = tile * 64;
        __syncthreads();             // all waves done reading At of previous tile
        // ---- stage A: 8 iters x 512 thr x 8B(bf16); fp32 read 16B/thread ----
#pragma unroll
        for (int c = 0; c < 8; ++c) {
            const int lin8 = c * 4096 + tid * 8;
            const int r_lin = lin8 >> 9;
            int grow = row0 + r_lin;
            if (grow >= N_NODES) grow = N_NODES - 1;
            const int colb = lin8 & 511;
            const float4 v = *reinterpret_cast<const float4*>(&A[(size_t)grow * IN_F + (colb >> 1)]);
            uint2 o;
            o.x = (unsigned)f2bf(v.x) | ((unsigned)f2bf(v.y) << 16);
            o.y = (unsigned)f2bf(v.z) | ((unsigned)f2bf(v.w) << 16);
            *reinterpret_cast<uint2*>(&At[lin8 ^ ((r_lin & 7) << 4)]) = o;
        }
        __syncthreads();

        f32x4 acc[4][4] = {};
#pragma unroll
        for (int ks = 0; ks < 8; ++ks) {
            bf16x8 af[4];
            const int kx = ((ks << 6) + klg) ^ xr;
#pragma unroll
            for (int m = 0; m < 4; ++m)
                af[m] = *reinterpret_cast<const bf16x8*>(&At[rowbase[m] + kx]);
#pragma unroll
            for (int m = 0; m < 4; ++m)
#pragma unroll
                for (int n = 0; n < 4; ++n)
                    acc[m][n] = __builtin_amdgcn_mfma_f32_16x16x32_bf16(bfr[ks][n], af[m], acc[m][n], 0, 0, 0);
        }
        // acc[m][n][r]: node=row0+m*16+lr, channel (in group) n*16+lg*4+r

        if (wid < 4) {
            const int h = wid;
            float4 alv[4], arv[4];
#pragma unroll
            for (int n = 0; n < 4; ++n) {
                alv[n] = *reinterpret_cast<const float4*>(&a_l[h * D_HEAD + n * 16 + lg * 4]);
                arv[n] = *reinterpret_cast<const float4*>(&a_r[h * D_HEAD + n * 16 + lg * 4]);
            }
#pragma unroll
            for (int m = 0; m < 4; ++m) {
                const int node = row0 + m * 16 + lr;
                float dl = 0.f, dr = 0.f;
                u64 pk[4];
#pragma unroll
                for (int n = 0; n < 4; ++n) {
                    float v0 = acc[m][n][0], v1 = acc[m][n][1], v2 = acc[m][n][2], v3 = acc[m][n][3];
                    v0 = isnan(v0) ? 0.f : v0;
                    v1 = isnan(v1) ? 0.f : v1;
                    v2 = isnan(v2) ? 0.f : v2;
                    v3 = isnan(v3) ? 0.f : v3;
                    dl += v0 * alv[n].x + v1 * alv[n].y + v2 * alv[n].z + v3 * alv[n].w;
                    dr += v0 * arv[n].x + v1 * arv[n].y + v2 * arv[n].z + v3 * arv[n].w;
                    pk[n] = (u64)f2bf(v0) | ((u64)f2bf(v1) << 16) |
                            ((u64)f2bf(v2) << 32) | ((u64)f2bf(v3) << 48);
                }
                if (node < N_NODES) {
                    const size_t base = (size_t)node * HD + h * D_HEAD + lg * 4;
#pragma unroll
                    for (int n = 0; n < 4; ++n)
                        *reinterpret_cast<u64*>(&emb_bf[base + n * 16]) = pk[n];
                }
                dl += __shfl_xor(dl, 16, 64); dr += __shfl_xor(dr, 16, 64);
                dl += __shfl_xor(dl, 32, 64); dr += __shfl_xor(dr, 32, 64);
                if (lg == 0 && node < N_NODES) {
                    s_l[node * H_HEADS + h] = dl;
                    s_r[node * H_HEADS + h] = dr;
                }
            }
        } else {
            const int c0 = (wid - 4) * 64 + lg * 4;
            float4 rb[4];
#pragma unroll
            for (int n = 0; n < 4; ++n)
                rb[n] = *reinterpret_cast<const float4*>(&resb[c0 + n * 16]);
#pragma unroll
            for (int m = 0; m < 4; ++m) {
                const int node = row0 + m * 16 + lr;
                if (node < N_NODES) {
                    const size_t base = (size_t)node * HD + c0;
#pragma unroll
                    for (int n = 0; n < 4; ++n) {
                        float4 o;
                        o.x = acc[m][n][0] + rb[n].x;
                        o.y = acc[m][n][1] + rb[n].y;
                        o.z = acc[m][n][2] + rb[n].z;
                        o.w = acc[m][n][3] + rb[n].w;
                        *reinterpret_cast<float4*>(&outp[base + n * 16]) = o;
                    }
                }
            }
        }
    }
}

// ---------------- K3: per-edge attention exponentials ----------------
// exw[e] = exp(leaky_relu(s_l[row] + s_r[col] + s_e[tp])) for all 4 heads
__global__ void k_edge(const int* __restrict__ row, const int* __restrict__ col,
                       const int* __restrict__ tp, const float* __restrict__ s_l,
                       const float* __restrict__ s_r, const float* __restrict__ s_e,
                       float4* __restrict__ exw) {
    const int e = blockIdx.x * 256 + threadIdx.x;
    if (e >= E_EDGES) return;
    const int r = row[e], c = col[e], t = tp[e];
    const float4 sl = *reinterpret_cast<const float4*>(&s_l[r * 4]);
    const float4 sr = *reinterpret_cast<const float4*>(&s_r[c * 4]);
    const float4 se = *reinterpret_cast<const float4*>(&s_e[t * 4]);
    float4 ex;
    float x;
    x = sl.x + sr.x + se.x; x = (x > 0.f) ? x : SLOPE * x; ex.x = __expf(x);
    x = sl.y + sr.y + se.y; x = (x > 0.f) ? x : SLOPE * x; ex.y = __expf(x);
    x = sl.z + sr.z + se.z; x = (x > 0.f) ? x : SLOPE * x; ex.z = __expf(x);
    x = sl.w + sr.w + se.w; x = (x > 0.f) ? x : SLOPE * x; ex.w = __expf(x);
    exw[e] = ex;
}

// ---------------- CSR build ----------------
__global__ void k_hist(const int* __restrict__ col, int* __restrict__ counts) {
    int e = blockIdx.x * 256 + threadIdx.x;
    if (e < E_EDGES) atomicAdd(&counts[col[e]], 1);
}

__global__ void k_scan1(const int* __restrict__ counts, int* __restrict__ row_ptr,
                        int* __restrict__ partials) {
    __shared__ int sd[256];
    const int t = threadIdx.x, b = blockIdx.x;
    const int base = b * 1024 + t * 4;
    int v[4];
#pragma unroll
    for (int j = 0; j < 4; ++j) v[j] = (base + j < N_NODES) ? counts[base + j] : 0;
    const int s = v[0] + v[1] + v[2] + v[3];
    sd[t] = s;
    __syncthreads();
    for (int off = 1; off < 256; off <<= 1) {
        int y = (t >= off) ? sd[t - off] : 0;
        __syncthreads();
        sd[t] += y;
        __syncthreads();
    }
    int p = sd[t] - s;
#pragma unroll
    for (int j = 0; j < 4; ++j) {
        if (base + j < N_NODES) row_ptr[base + j] = p;
        p += v[j];
    }
    if (t == 255) partials[b] = sd[255];
}

__global__ void k_scan2(int* __restrict__ partials) {
    __shared__ int sd[128];
    const int t = threadIdx.x;
    const int v = (t < 98) ? partials[t] : 0;
    sd[t] = v;
    __syncthreads();
    for (int off = 1; off < 128; off <<= 1) {
        int y = (t >= off) ? sd[t - off] : 0;
        __syncthreads();
        sd[t] += y;
        __syncthreads();
    }
    if (t < 98) partials[t] = sd[t] - v;
}

__global__ void k_scan3(int* __restrict__ row_ptr, int* __restrict__ fill,
                        const int* __restrict__ partials) {
    const int i = blockIdx.x * 256 + threadIdx.x;
    if (i < N_NODES) {
        const int v = row_ptr[i] + partials[i >> 10];
        row_ptr[i] = v;
        fill[i] = v;
    }
    if (i == 0) row_ptr[N_NODES] = E_EDGES;
}

__global__ void k_scatter(const int* __restrict__ row, const int* __restrict__ col,
                          int* __restrict__ fill, u64* __restrict__ perm_re) {
    int e = blockIdx.x * 256 + threadIdx.x;
    if (e < E_EDGES) {
        int c = col[e];
        int p = atomicAdd(&fill[c], 1);
        perm_re[p] = (u64)(unsigned)row[e] | ((u64)(unsigned)e << 32);
    }
}

// ---------------- K5: per-destination aggregation (one wave per node, 4-wide) -------------
__global__ __launch_bounds__(256)
void k_aggregate(const int* __restrict__ row_ptr, const u64* __restrict__ perm_re,
                 const u16* __restrict__ emb_bf, const float* __restrict__ exw,
                 float* __restrict__ outp) {
    const int wave = threadIdx.x >> 6;
    const int lane = threadIdx.x & 63;
    const int n = blockIdx.x * 4 + wave;           // grid = N/4 exactly
    const int h = lane >> 4;                       // this lane's head
    const int start = row_ptr[n], end = row_ptr[n + 1];
    const size_t o = (size_t)n * HD + lane * 4;
    const float4 res = *reinterpret_cast<const float4*>(&outp[o]);

    float a0 = 0.f, a1 = 0.f, a2 = 0.f, a3 = 0.f, den = 0.f;
    int i = start;
    for (; i + 4 <= end; i += 4) {
        const u64 q0 = perm_re[i],     q1 = perm_re[i + 1];
        const u64 q2 = perm_re[i + 2], q3 = perm_re[i + 3];
        const int r0 = (int)(unsigned)q0, r1 = (int)(unsigned)q1;
        const int r2 = (int)(unsigned)q2, r3 = (int)(unsigned)q3;
        const float ex0 = exw[((q0 >> 32) << 2) + h];
        const float ex1 = exw[((q1 >> 32) << 2) + h];
        const float ex2 = exw[((q2 >> 32) << 2) + h];
        const float ex3 = exw[((q3 >> 32) << 2) + h];
        const u64 ev0 = *reinterpret_cast<const u64*>(&emb_bf[(size_t)r0 * HD + lane * 4]);
        const u64 ev1 = *reinterpret_cast<const u64*>(&emb_bf[(size_t)r1 * HD + lane * 4]);
        const u64 ev2 = *reinterpret_cast<const u64*>(&emb_bf[(size_t)r2 * HD + lane * 4]);
        const u64 ev3 = *reinterpret_cast<const u64*>(&emb_bf[(size_t)r3 * HD + lane * 4]);
        a0 += ex0 * bf2f((unsigned)(ev0) & 0xFFFFu)       + ex1 * bf2f((unsigned)(ev1) & 0xFFFFu)
            + ex2 * bf2f((unsigned)(ev2) & 0xFFFFu)       + ex3 * bf2f((unsigned)(ev3) & 0xFFFFu);
        a1 += ex0 * bf2f((unsigned)(ev0 >> 16) & 0xFFFFu) + ex1 * bf2f((unsigned)(ev1 >> 16) & 0xFFFFu)
            + ex2 * bf2f((unsigned)(ev2 >> 16) & 0xFFFFu) + ex3 * bf2f((unsigned)(ev3 >> 16) & 0xFFFFu);
        a2 += ex0 * bf2f((unsigned)(ev0 >> 32) & 0xFFFFu) + ex1 * bf2f((unsigned)(ev1 >> 32) & 0xFFFFu)
            + ex2 * bf2f((unsigned)(ev2 >> 32) & 0xFFFFu) + ex3 * bf2f((unsigned)(ev3 >> 32) & 0xFFFFu);
        a3 += ex0 * bf2f((unsigned)(ev0 >> 48) & 0xFFFFu) + ex1 * bf2f((unsigned)(ev1 >> 48) & 0xFFFFu)
            + ex2 * bf2f((unsigned)(ev2 >> 48) & 0xFFFFu) + ex3 * bf2f((unsigned)(ev3 >> 48) & 0xFFFFu);
        den += ex0 + ex1 + ex2 + ex3;
    }
    for (; i < end; ++i) {
        const u64 q0 = perm_re[i];
        const int r0 = (int)(unsigned)q0;
        const float ex0 = exw[((q0 >> 32) << 2) + h];
        const u64 ev0 = *reinterpret_cast<const u64*>(&emb_bf[(size_t)r0 * HD + lane * 4]);
        a0 += ex0 * bf2f((unsigned)(ev0) & 0xFFFFu);
        a1 += ex0 * bf2f((unsigned)(ev0 >> 16) & 0xFFFFu);
        a2 += ex0 * bf2f((unsigned)(ev0 >> 32) & 0xFFFFu);
        a3 += ex0 * bf2f((unsigned)(ev0 >> 48) & 0xFFFFu);
        den += ex0;
    }
    const float inv = (den > 0.f) ? 1.f / den : 0.f;
    float4 out;
    float x;
    x = a0 * inv + res.x; out.x = (x > 0.f) ? x : __expf(x) - 1.f;
    x = a1 * inv + res.y; out.y = (x > 0.f) ? x : __expf(x) - 1.f;
    x = a2 * inv + res.z; out.z = (x > 0.f) ? x : __expf(x) - 1.f;
    x = a3 * inv + res.w; out.w = (x > 0.f) ? x : __expf(x) - 1.f;
    *reinterpret_cast<float4*>(&outp[o]) = out;
}

extern "C" void kernel_launch(void* const* d_in, const int* in_sizes, int n_in,
                              void* d_out, int out_size, void* d_ws, size_t ws_size,
                              hipStream_t stream) {
    const float* h    = (const float*)d_in[0];
    const float* W    = (const float*)d_in[1];
    const float* W_e  = (const float*)d_in[2];
    const float* eemb = (const float*)d_in[3];
    const float* a_l  = (const float*)d_in[4];
    const float* a_r  = (const float*)d_in[5];
    const float* a_e  = (const float*)d_in[6];
    const float* resW = (const float*)d_in[7];
    const float* resb = (const float*)d_in[8];
    const int* row = (const int*)d_in[9];
    const int* col = (const int*)d_in[10];
    const int* tp  = (const int*)d_in[11];
    float* outp = (float*)d_out;

    char* ws = (char*)d_ws;
    size_t off = 0;
    auto alloc = [&](size_t b) { size_t o = off; off += (b + 255) & ~(size_t)255; return o; };
    u16*  Bfrag   = (u16*)(ws + alloc((size_t)512 * IN_F * 2));
    u16*  emb_bf  = (u16*)(ws + alloc((size_t)N_NODES * HD * 2));
    float* s_l    = (float*)(ws + alloc((size_t)N_NODES * H_HEADS * 4));
    float* s_r    = (float*)(ws + alloc((size_t)N_NODES * H_HEADS * 4));
    float* s_e    = (float*)(ws + alloc(NET_T * H_HEADS * 4));
    int*  counts  = (int*)(ws + alloc((size_t)N_NODES * 4));
    int*  row_ptr = (int*)(ws + alloc((size_t)(N_NODES + 1) * 4));
    int*  fill    = (int*)(ws + alloc((size_t)N_NODES * 4));
    u64*  perm_re = (u64*)(ws + alloc((size_t)E_EDGES * 8));
    float* exw    = (float*)(ws + alloc((size_t)E_EDGES * H_HEADS * 4));
    int*  partials= (int*)(ws + alloc(128 * 4));

    k_se<<<1, 256, 0, stream>>>(eemb, W_e, a_e, s_e);
    k_prep_w<<<64, 256, 0, stream>>>(W, resW, Bfrag);
    k_mfma<<<512, 512, 0, stream>>>(h, Bfrag, a_l, a_r, resb, emb_bf, s_l, s_r, outp);
    hipMemsetAsync(counts, 0, (size_t)N_NODES * 4, stream);
    k_hist<<<(E_EDGES + 255) / 256, 256, 0, stream>>>(col, counts);
    k_scan1<<<98, 256, 0, stream>>>(counts, row_ptr, partials);
    k_scan2<<<1, 128, 0, stream>>>(partials);
    k_scan3<<<(N_NODES + 255) / 256, 256, 0, stream>>>(row_ptr, fill, partials);
    k_scatter<<<(E_EDGES + 255) / 256, 256, 0, stream>>>(row, col, fill, perm_re);
    k_edge<<<(E_EDGES + 255) / 256, 256, 0, stream>>>(row, col, tp, s_l, s_r, s_e, (float4*)exw);
    k_aggregate<<<N_NODES / 4, 256, 0, stream>>>(row_ptr, perm_re, emb_bf, exw, outp);
}

// Round 6
// 311.460 us; speedup vs baseline: 1.1748x; 1.1748x over previous
//
#include <hip/hip_runtime.h>

#define N_NODES 100000
#define E_EDGES 800000
#define IN_F 256
#define D_HEAD 64
#define H_HEADS 4
#define EF_F 64
#define NET_T 8
#define HD 256          // H*D
#define SLOPE 0.2f
#define NTILES ((N_NODES + 63) / 64)

typedef unsigned short u16;
typedef unsigned long long u64;
typedef __attribute__((ext_vector_type(8))) short bf16x8;
typedef __attribute__((ext_vector_type(4))) float f32x4;

static __device__ __forceinline__ u16 f2bf(float f) {
    unsigned int u = __float_as_uint(f);
    unsigned int r = u + 0x7FFFu + ((u >> 16) & 1u);
    return (u16)(r >> 16);
}
static __device__ __forceinline__ float bf2f(unsigned int u) {
    return __uint_as_float(u << 16);
}

// ---------------- K0: s_e[t][h] = sum_f a_e[h,f] * (edge_emb @ W_e)[t,h,f] ----------------
__global__ void k_se(const float* __restrict__ edge_emb, const float* __restrict__ W_e,
                     const float* __restrict__ a_e, float* __restrict__ s_e) {
    int tid = threadIdx.x;           // 256 threads
    int t  = tid >> 5;               // 0..7
    int h  = (tid >> 3) & 3;         // 0..3
    int fc = tid & 7;                // 0..7
    float part = 0.f;
    for (int j = 0; j < 8; ++j) {
        int f = fc * 8 + j;
        float acc = 0.f;
        for (int k = 0; k < EF_F; ++k)
            acc += edge_emb[t * EF_F + k] * W_e[k * (EF_F * H_HEADS) + h * EF_F + f];
        part += a_e[h * EF_F + f] * acc;
    }
    for (int off = 1; off < 8; off <<= 1)
        part += __shfl_xor(part, off, 64);
    if (fc == 0) s_e[t * H_HEADS + h] = part;
}

// ---------------- K1: Bfrag[g][ks][n][lane] fragment-major bf16 of [W | res_W]^T ----------
__global__ void k_prep_w(const float* __restrict__ W, const float* __restrict__ resW,
                         u16* __restrict__ Bfrag) {
    const int gid = blockIdx.x * 256 + threadIdx.x;   // 16384 total
    const int lane = gid & 63;
    const int fragid = gid >> 6;          // 0..255 = g*32 + ks*4 + n
    const int n = fragid & 3;
    const int ks = (fragid >> 2) & 7;
    const int g = fragid >> 5;            // 0..7
    const int c = g * 64 + n * 16 + (lane & 15);      // 0..511
    const int k0 = ks * 32 + (lane >> 4) * 8;
    const float* src = (c < HD) ? &W[c] : &resW[c - HD];
    u16 tmp[8];
#pragma unroll
    for (int j = 0; j < 8; ++j)
        tmp[j] = f2bf(src[(size_t)(k0 + j) * HD]);
    *reinterpret_cast<uint4*>(&Bfrag[(size_t)fragid * 512 + lane * 8]) =
        *reinterpret_cast<const uint4*>(tmp);
}

// ---------------- K2: fused convert + MFMA GEMM (operand-swapped, D[ch][node]) ------------
// R4 structure: one 64-row tile per block, 512 thr = 8 waves, B fragments streamed
// from L2 inside the k-loop, A staged once to XOR-swizzled LDS.
__global__ __launch_bounds__(512, 2)
void k_mfma(const float* __restrict__ A, const u16* __restrict__ Bfrag,
            const float* __restrict__ a_l, const float* __restrict__ a_r,
            const float* __restrict__ resb,
            u16* __restrict__ emb_bf, float* __restrict__ s_l, float* __restrict__ s_r,
            float* __restrict__ outp) {
    __shared__ char At[32768];       // 64 rows x 256 bf16, XOR-swizzled
    const int tid = threadIdx.x;
    const int lane = tid & 63;
    const int wid = tid >> 6;        // 0..7 = channel-group
    const int row0 = blockIdx.x * 64;

    // ---- stage: 8 iters x 512 thr x 8B(bf16); fp32 read 16B/thread ----
#pragma unroll
    for (int c = 0; c < 8; ++c) {
        const int lin8 = c * 4096 + tid * 8;          // linear byte in bf16 tile
        const int r_lin = lin8 >> 9;                  // tile row 0..63
        int grow = row0 + r_lin;
        if (grow >= N_NODES) grow = N_NODES - 1;      // clamp (stores masked later)
        const int colb = lin8 & 511;
        const float4 v = *reinterpret_cast<const float4*>(&A[(size_t)grow * IN_F + (colb >> 1)]);
        uint2 o;
        o.x = (unsigned)f2bf(v.x) | ((unsigned)f2bf(v.y) << 16);
        o.y = (unsigned)f2bf(v.z) | ((unsigned)f2bf(v.w) << 16);
        *reinterpret_cast<uint2*>(&At[lin8 ^ ((r_lin & 7) << 4)]) = o;
    }
    __syncthreads();

    const int lr = lane & 15;
    const int lg = lane >> 4;
    const int xr = (lr & 7) << 4;                     // swizzle term
    const int klg = lg * 16;                          // byte k-chunk offset in row

    int rowbase[4];
#pragma unroll
    for (int m = 0; m < 4; ++m) rowbase[m] = (m * 16 + lr) * 512;

    const u16* bp = Bfrag + (size_t)wid * 16384 + lane * 8;

    f32x4 acc[4][4] = {};
#pragma unroll
    for (int ks = 0; ks < 8; ++ks) {
        bf16x8 af[4], bfr[4];
        const int kx = ((ks << 6) + klg) ^ xr;        // swizzled intra-row byte
#pragma unroll
        for (int n = 0; n < 4; ++n)
            bfr[n] = *reinterpret_cast<const bf16x8*>(&bp[ks * 2048 + n * 512]);
#pragma unroll
        for (int m = 0; m < 4; ++m)
            af[m] = *reinterpret_cast<const bf16x8*>(&At[rowbase[m] + kx]);
#pragma unroll
        for (int m = 0; m < 4; ++m)
#pragma unroll
            for (int n = 0; n < 4; ++n)
                acc[m][n] = __builtin_amdgcn_mfma_f32_16x16x32_bf16(bfr[n], af[m], acc[m][n], 0, 0, 0);
    }
    // acc[m][n][r]: node=row0+m*16+lr, channel (within group) n*16+lg*4+r

    if (wid < 4) {
        const int h = wid;
        float4 alv[4], arv[4];
#pragma unroll
        for (int n = 0; n < 4; ++n) {
            alv[n] = *reinterpret_cast<const float4*>(&a_l[h * D_HEAD + n * 16 + lg * 4]);
            arv[n] = *reinterpret_cast<const float4*>(&a_r[h * D_HEAD + n * 16 + lg * 4]);
        }
#pragma unroll
        for (int m = 0; m < 4; ++m) {
            const int node = row0 + m * 16 + lr;
            float dl = 0.f, dr = 0.f;
            u64 pk[4];
#pragma unroll
            for (int n = 0; n < 4; ++n) {
                float v0 = acc[m][n][0], v1 = acc[m][n][1], v2 = acc[m][n][2], v3 = acc[m][n][3];
                v0 = isnan(v0) ? 0.f : v0;            // nan_to_num
                v1 = isnan(v1) ? 0.f : v1;
                v2 = isnan(v2) ? 0.f : v2;
                v3 = isnan(v3) ? 0.f : v3;
                dl += v0 * alv[n].x + v1 * alv[n].y + v2 * alv[n].z + v3 * alv[n].w;
                dr += v0 * arv[n].x + v1 * arv[n].y + v2 * arv[n].z + v3 * arv[n].w;
                pk[n] = (u64)f2bf(v0) | ((u64)f2bf(v1) << 16) |
                        ((u64)f2bf(v2) << 32) | ((u64)f2bf(v3) << 48);
            }
            if (node < N_NODES) {
                const size_t base = (size_t)node * HD + h * D_HEAD + lg * 4;
#pragma unroll
                for (int n = 0; n < 4; ++n)
                    *reinterpret_cast<u64*>(&emb_bf[base + n * 16]) = pk[n];
            }
            dl += __shfl_xor(dl, 16, 64); dr += __shfl_xor(dr, 16, 64);
            dl += __shfl_xor(dl, 32, 64); dr += __shfl_xor(dr, 32, 64);
            if (lg == 0 && node < N_NODES) {
                s_l[node * H_HEADS + h] = dl;
                s_r[node * H_HEADS + h] = dr;
            }
        }
    } else {
        const int c0 = (wid - 4) * 64 + lg * 4;
        float4 rb[4];
#pragma unroll
        for (int n = 0; n < 4; ++n)
            rb[n] = *reinterpret_cast<const float4*>(&resb[c0 + n * 16]);
#pragma unroll
        for (int m = 0; m < 4; ++m) {
            const int node = row0 + m * 16 + lr;
            if (node < N_NODES) {
                const size_t base = (size_t)node * HD + c0;
#pragma unroll
                for (int n = 0; n < 4; ++n) {
                    float4 o;
                    o.x = acc[m][n][0] + rb[n].x;
                    o.y = acc[m][n][1] + rb[n].y;
                    o.z = acc[m][n][2] + rb[n].z;
                    o.w = acc[m][n][3] + rb[n].w;
                    *reinterpret_cast<float4*>(&outp[base + n * 16]) = o;
                }
            }
        }
    }
}

// ---------------- CSR build ----------------
__global__ void k_hist(const int* __restrict__ col, int* __restrict__ counts) {
    int e = blockIdx.x * 256 + threadIdx.x;
    if (e < E_EDGES) atomicAdd(&counts[col[e]], 1);
}

__global__ void k_scan1(const int* __restrict__ counts, int* __restrict__ row_ptr,
                        int* __restrict__ partials) {
    __shared__ int sd[256];
    const int t = threadIdx.x, b = blockIdx.x;
    const int base = b * 1024 + t * 4;
    int v[4];
#pragma unroll
    for (int j = 0; j < 4; ++j) v[j] = (base + j < N_NODES) ? counts[base + j] : 0;
    const int s = v[0] + v[1] + v[2] + v[3];
    sd[t] = s;
    __syncthreads();
    for (int off = 1; off < 256; off <<= 1) {
        int y = (t >= off) ? sd[t - off] : 0;
        __syncthreads();
        sd[t] += y;
        __syncthreads();
    }
    int p = sd[t] - s;
#pragma unroll
    for (int j = 0; j < 4; ++j) {
        if (base + j < N_NODES) row_ptr[base + j] = p;
        p += v[j];
    }
    if (t == 255) partials[b] = sd[255];
}

__global__ void k_scan2(int* __restrict__ partials) {
    __shared__ int sd[128];
    const int t = threadIdx.x;
    const int v = (t < 98) ? partials[t] : 0;
    sd[t] = v;
    __syncthreads();
    for (int off = 1; off < 128; off <<= 1) {
        int y = (t >= off) ? sd[t - off] : 0;
        __syncthreads();
        sd[t] += y;
        __syncthreads();
    }
    if (t < 98) partials[t] = sd[t] - v;
}

__global__ void k_scan3(int* __restrict__ row_ptr, int* __restrict__ fill,
                        const int* __restrict__ partials) {
    const int i = blockIdx.x * 256 + threadIdx.x;
    if (i < N_NODES) {
        const int v = row_ptr[i] + partials[i >> 10];
        row_ptr[i] = v;
        fill[i] = v;
    }
    if (i == 0) row_ptr[N_NODES] = E_EDGES;
}

// ---------------- K4: scatter + per-edge attention exp, permuted outputs ----------------
__global__ void k_scatter(const int* __restrict__ row, const int* __restrict__ col,
                          const int* __restrict__ tp, const float* __restrict__ s_l,
                          const float* __restrict__ s_r, const float* __restrict__ s_e,
                          int* __restrict__ fill, int* __restrict__ perm_row,
                          float4* __restrict__ exw_perm) {
    const int e = blockIdx.x * 256 + threadIdx.x;
    if (e >= E_EDGES) return;
    const int r = row[e], c = col[e], t = tp[e];
    const float4 sl = *reinterpret_cast<const float4*>(&s_l[r * 4]);
    const float4 sr = *reinterpret_cast<const float4*>(&s_r[c * 4]);
    const float4 se = *reinterpret_cast<const float4*>(&s_e[t * 4]);
    float4 ex;
    float x;
    x = sl.x + sr.x + se.x; x = (x > 0.f) ? x : SLOPE * x; ex.x = __expf(x);
    x = sl.y + sr.y + se.y; x = (x > 0.f) ? x : SLOPE * x; ex.y = __expf(x);
    x = sl.z + sr.z + se.z; x = (x > 0.f) ? x : SLOPE * x; ex.z = __expf(x);
    x = sl.w + sr.w + se.w; x = (x > 0.f) ? x : SLOPE * x; ex.w = __expf(x);
    const int p = atomicAdd(&fill[c], 1);
    perm_row[p] = r;
    exw_perm[p] = ex;
}

// ---------------- K5: per-destination aggregation (one wave per node, 4-wide) -------------
__global__ __launch_bounds__(256)
void k_aggregate(const int* __restrict__ row_ptr, const int* __restrict__ perm_row,
                 const float* __restrict__ exw_perm,
                 const u16* __restrict__ emb_bf, float* __restrict__ outp) {
    const int wave = threadIdx.x >> 6;
    const int lane = threadIdx.x & 63;
    const int n = blockIdx.x * 4 + wave;           // grid = N/4 exactly
    const int h = lane >> 4;                       // this lane's head
    const int start = row_ptr[n], end = row_ptr[n + 1];
    const size_t o = (size_t)n * HD + lane * 4;
    const float4 res = *reinterpret_cast<const float4*>(&outp[o]);

    float a0 = 0.f, a1 = 0.f, a2 = 0.f, a3 = 0.f, den = 0.f;
    int i = start;
    for (; i + 4 <= end; i += 4) {
        const int r0 = perm_row[i],     r1 = perm_row[i + 1];
        const int r2 = perm_row[i + 2], r3 = perm_row[i + 3];
        const float ex0 = exw_perm[(i)     * 4 + h];
        const float ex1 = exw_perm[(i + 1) * 4 + h];
        const float ex2 = exw_perm[(i + 2) * 4 + h];
        const float ex3 = exw_perm[(i + 3) * 4 + h];
        const u64 ev0 = *reinterpret_cast<const u64*>(&emb_bf[(size_t)r0 * HD + lane * 4]);
        const u64 ev1 = *reinterpret_cast<const u64*>(&emb_bf[(size_t)r1 * HD + lane * 4]);
        const u64 ev2 = *reinterpret_cast<const u64*>(&emb_bf[(size_t)r2 * HD + lane * 4]);
        const u64 ev3 = *reinterpret_cast<const u64*>(&emb_bf[(size_t)r3 * HD + lane * 4]);
        a0 += ex0 * bf2f((unsigned)(ev0) & 0xFFFFu)       + ex1 * bf2f((unsigned)(ev1) & 0xFFFFu)
            + ex2 * bf2f((unsigned)(ev2) & 0xFFFFu)       + ex3 * bf2f((unsigned)(ev3) & 0xFFFFu);
        a1 += ex0 * bf2f((unsigned)(ev0 >> 16) & 0xFFFFu) + ex1 * bf2f((unsigned)(ev1 >> 16) & 0xFFFFu)
            + ex2 * bf2f((unsigned)(ev2 >> 16) & 0xFFFFu) + ex3 * bf2f((unsigned)(ev3 >> 16) & 0xFFFFu);
        a2 += ex0 * bf2f((unsigned)(ev0 >> 32) & 0xFFFFu) + ex1 * bf2f((unsigned)(ev1 >> 32) & 0xFFFFu)
            + ex2 * bf2f((unsigned)(ev2 >> 32) & 0xFFFFu) + ex3 * bf2f((unsigned)(ev3 >> 32) & 0xFFFFu);
        a3 += ex0 * bf2f((unsigned)(ev0 >> 48) & 0xFFFFu) + ex1 * bf2f((unsigned)(ev1 >> 48) & 0xFFFFu)
            + ex2 * bf2f((unsigned)(ev2 >> 48) & 0xFFFFu) + ex3 * bf2f((unsigned)(ev3 >> 48) & 0xFFFFu);
        den += ex0 + ex1 + ex2 + ex3;
    }
    for (; i < end; ++i) {
        const int r0 = perm_row[i];
        const float ex0 = exw_perm[i * 4 + h];
        const u64 ev0 = *reinterpret_cast<const u64*>(&emb_bf[(size_t)r0 * HD + lane * 4]);
        a0 += ex0 * bf2f((unsigned)(ev0) & 0xFFFFu);
        a1 += ex0 * bf2f((unsigned)(ev0 >> 16) & 0xFFFFu);
        a2 += ex0 * bf2f((unsigned)(ev0 >> 32) & 0xFFFFu);
        a3 += ex0 * bf2f((unsigned)(ev0 >> 48) & 0xFFFFu);
        den += ex0;
    }
    const float inv = (den > 0.f) ? 1.f / den : 0.f;
    float4 out;
    float x;
    x = a0 * inv + res.x; out.x = (x > 0.f) ? x : __expf(x) - 1.f;
    x = a1 * inv + res.y; out.y = (x > 0.f) ? x : __expf(x) - 1.f;
    x = a2 * inv + res.z; out.z = (x > 0.f) ? x : __expf(x) - 1.f;
    x = a3 * inv + res.w; out.w = (x > 0.f) ? x : __expf(x) - 1.f;
    *reinterpret_cast<float4*>(&outp[o]) = out;
}

extern "C" void kernel_launch(void* const* d_in, const int* in_sizes, int n_in,
                              void* d_out, int out_size, void* d_ws, size_t ws_size,
                              hipStream_t stream) {
    const float* h    = (const float*)d_in[0];
    const float* W    = (const float*)d_in[1];
    const float* W_e  = (const float*)d_in[2];
    const float* eemb = (const float*)d_in[3];
    const float* a_l  = (const float*)d_in[4];
    const float* a_r  = (const float*)d_in[5];
    const float* a_e  = (const float*)d_in[6];
    const float* resW = (const float*)d_in[7];
    const float* resb = (const float*)d_in[8];
    const int* row = (const int*)d_in[9];
    const int* col = (const int*)d_in[10];
    const int* tp  = (const int*)d_in[11];
    float* outp = (float*)d_out;

    char* ws = (char*)d_ws;
    size_t off = 0;
    auto alloc = [&](size_t b) { size_t o = off; off += (b + 255) & ~(size_t)255; return o; };
    u16*  Bfrag   = (u16*)(ws + alloc((size_t)512 * IN_F * 2));
    u16*  emb_bf  = (u16*)(ws + alloc((size_t)N_NODES * HD * 2));
    float* s_l    = (float*)(ws + alloc((size_t)N_NODES * H_HEADS * 4));
    float* s_r    = (float*)(ws + alloc((size_t)N_NODES * H_HEADS * 4));
    float* s_e    = (float*)(ws + alloc(NET_T * H_HEADS * 4));
    int*  counts  = (int*)(ws + alloc((size_t)N_NODES * 4));
    int*  row_ptr = (int*)(ws + alloc((size_t)(N_NODES + 1) * 4));
    int*  fill    = (int*)(ws + alloc((size_t)N_NODES * 4));
    int*  perm_row= (int*)(ws + alloc((size_t)E_EDGES * 4));
    float* exw_perm=(float*)(ws + alloc((size_t)E_EDGES * H_HEADS * 4));
    int*  partials= (int*)(ws + alloc(128 * 4));

    k_se<<<1, 256, 0, stream>>>(eemb, W_e, a_e, s_e);
    k_prep_w<<<64, 256, 0, stream>>>(W, resW, Bfrag);
    k_mfma<<<NTILES, 512, 0, stream>>>(h, Bfrag, a_l, a_r, resb, emb_bf, s_l, s_r, outp);
    hipMemsetAsync(counts, 0, (size_t)N_NODES * 4, stream);
    k_hist<<<(E_EDGES + 255) / 256, 256, 0, stream>>>(col, counts);
    k_scan1<<<98, 256, 0, stream>>>(counts, row_ptr, partials);
    k_scan2<<<1, 128, 0, stream>>>(partials);
    k_scan3<<<(N_NODES + 255) / 256, 256, 0, stream>>>(row_ptr, fill, partials);
    k_scatter<<<(E_EDGES + 255) / 256, 256, 0, stream>>>(row, col, tp, s_l, s_r, s_e,
                                                         fill, perm_row, (float4*)exw_perm);
    k_aggregate<<<N_NODES / 4, 256, 0, stream>>>(row_ptr, perm_row, exw_perm, emb_bf, outp);
}

// Round 7
// 308.718 us; speedup vs baseline: 1.1852x; 1.0089x over previous
//
#include <hip/hip_runtime.h>

#define N_NODES 100000
#define E_EDGES 800000
#define IN_F 256
#define D_HEAD 64
#define H_HEADS 4
#define EF_F 64
#define NET_T 8
#define HD 256          // H*D
#define SLOPE 0.2f
#define NTILES ((N_NODES + 63) / 64)

typedef unsigned short u16;
typedef unsigned long long u64;
typedef __attribute__((ext_vector_type(8))) short bf16x8;
typedef __attribute__((ext_vector_type(4))) float f32x4;

static __device__ __forceinline__ u16 f2bf(float f) {
    unsigned int u = __float_as_uint(f);
    unsigned int r = u + 0x7FFFu + ((u >> 16) & 1u);
    return (u16)(r >> 16);
}
static __device__ __forceinline__ float bf2f(unsigned int u) {
    return __uint_as_float(u << 16);
}

// ---------------- K0: s_e[t][h] = sum_f a_e[h,f] * (edge_emb @ W_e)[t,h,f] ----------------
__global__ void k_se(const float* __restrict__ edge_emb, const float* __restrict__ W_e,
                     const float* __restrict__ a_e, float* __restrict__ s_e) {
    int tid = threadIdx.x;           // 256 threads
    int t  = tid >> 5;               // 0..7
    int h  = (tid >> 3) & 3;         // 0..3
    int fc = tid & 7;                // 0..7
    float part = 0.f;
    for (int j = 0; j < 8; ++j) {
        int f = fc * 8 + j;
        float acc = 0.f;
        for (int k = 0; k < EF_F; ++k)
            acc += edge_emb[t * EF_F + k] * W_e[k * (EF_F * H_HEADS) + h * EF_F + f];
        part += a_e[h * EF_F + f] * acc;
    }
    for (int off = 1; off < 8; off <<= 1)
        part += __shfl_xor(part, off, 64);
    if (fc == 0) s_e[t * H_HEADS + h] = part;
}

// ---------------- K1: Bfrag[g][ks][n][lane] fragment-major bf16 of [W | res_W]^T ----------
__global__ void k_prep_w(const float* __restrict__ W, const float* __restrict__ resW,
                         u16* __restrict__ Bfrag) {
    const int gid = blockIdx.x * 256 + threadIdx.x;   // 16384 total
    const int lane = gid & 63;
    const int fragid = gid >> 6;          // 0..255 = g*32 + ks*4 + n
    const int n = fragid & 3;
    const int ks = (fragid >> 2) & 7;
    const int g = fragid >> 5;            // 0..7
    const int c = g * 64 + n * 16 + (lane & 15);      // 0..511
    const int k0 = ks * 32 + (lane >> 4) * 8;
    const float* src = (c < HD) ? &W[c] : &resW[c - HD];
    u16 tmp[8];
#pragma unroll
    for (int j = 0; j < 8; ++j)
        tmp[j] = f2bf(src[(size_t)(k0 + j) * HD]);
    *reinterpret_cast<uint4*>(&Bfrag[(size_t)fragid * 512 + lane * 8]) =
        *reinterpret_cast<const uint4*>(tmp);
}

// ---------------- K2: fused convert + MFMA GEMM (4-wave blocks, operand-swapped) ----------
// grid (NTILES, 2), 256 thr = 4 waves. by=0: emb heads (wave = head); by=1: residual
// col-groups (bf16 store to res_bf). A-tile (64x256) staged to XOR-swizzled LDS.
__global__ __launch_bounds__(256, 4)
void k_mfma(const float* __restrict__ A, const u16* __restrict__ Bfrag,
            const float* __restrict__ a_l, const float* __restrict__ a_r,
            const float* __restrict__ resb,
            u16* __restrict__ emb_bf, float* __restrict__ s_l, float* __restrict__ s_r,
            u16* __restrict__ res_bf) {
    __shared__ char At[32768];       // 64 rows x 256 bf16, XOR-swizzled
    const int tid = threadIdx.x;
    const int lane = tid & 63;
    const int wv = tid >> 6;         // 0..3
    const int by = blockIdx.y;       // 0: emb, 1: residual
    const int wid = (by << 2) | wv;  // global channel-group 0..7
    const int row0 = blockIdx.x * 64;

    // ---- stage: 16 iters x 256 thr x 8B(bf16); fp32 read 16B/thread ----
#pragma unroll
    for (int c = 0; c < 16; ++c) {
        const int lin8 = c * 2048 + tid * 8;          // linear byte in bf16 tile
        const int r_lin = lin8 >> 9;                  // tile row 0..63
        int grow = row0 + r_lin;
        if (grow >= N_NODES) grow = N_NODES - 1;      // clamp (stores masked later)
        const int colb = lin8 & 511;
        const float4 v = *reinterpret_cast<const float4*>(&A[(size_t)grow * IN_F + (colb >> 1)]);
        uint2 o;
        o.x = (unsigned)f2bf(v.x) | ((unsigned)f2bf(v.y) << 16);
        o.y = (unsigned)f2bf(v.z) | ((unsigned)f2bf(v.w) << 16);
        *reinterpret_cast<uint2*>(&At[lin8 ^ ((r_lin & 7) << 4)]) = o;
    }
    __syncthreads();

    const int lr = lane & 15;
    const int lg = lane >> 4;
    const int xr = (lr & 7) << 4;                     // swizzle term
    const int klg = lg * 16;                          // byte k-chunk offset in row

    int rowbase[4];
#pragma unroll
    for (int m = 0; m < 4; ++m) rowbase[m] = (m * 16 + lr) * 512;

    const u16* bp = Bfrag + (size_t)wid * 16384 + lane * 8;

    f32x4 acc[4][4] = {};
#pragma unroll
    for (int ks = 0; ks < 8; ++ks) {
        bf16x8 af[4], bfr[4];
        const int kx = ((ks << 6) + klg) ^ xr;        // swizzled intra-row byte
#pragma unroll
        for (int n = 0; n < 4; ++n)
            bfr[n] = *reinterpret_cast<const bf16x8*>(&bp[ks * 2048 + n * 512]);
#pragma unroll
        for (int m = 0; m < 4; ++m)
            af[m] = *reinterpret_cast<const bf16x8*>(&At[rowbase[m] + kx]);
#pragma unroll
        for (int m = 0; m < 4; ++m)
#pragma unroll
            for (int n = 0; n < 4; ++n)
                acc[m][n] = __builtin_amdgcn_mfma_f32_16x16x32_bf16(bfr[n], af[m], acc[m][n], 0, 0, 0);
    }
    // acc[m][n][r]: node=row0+m*16+lr, channel (within group) n*16+lg*4+r

    if (by == 0) {
        const int h = wv;
        float4 alv[4], arv[4];
#pragma unroll
        for (int n = 0; n < 4; ++n) {
            alv[n] = *reinterpret_cast<const float4*>(&a_l[h * D_HEAD + n * 16 + lg * 4]);
            arv[n] = *reinterpret_cast<const float4*>(&a_r[h * D_HEAD + n * 16 + lg * 4]);
        }
#pragma unroll
        for (int m = 0; m < 4; ++m) {
            const int node = row0 + m * 16 + lr;
            float dl = 0.f, dr = 0.f;
            u64 pk[4];
#pragma unroll
            for (int n = 0; n < 4; ++n) {
                float v0 = acc[m][n][0], v1 = acc[m][n][1], v2 = acc[m][n][2], v3 = acc[m][n][3];
                v0 = isnan(v0) ? 0.f : v0;            // nan_to_num
                v1 = isnan(v1) ? 0.f : v1;
                v2 = isnan(v2) ? 0.f : v2;
                v3 = isnan(v3) ? 0.f : v3;
                dl += v0 * alv[n].x + v1 * alv[n].y + v2 * alv[n].z + v3 * alv[n].w;
                dr += v0 * arv[n].x + v1 * arv[n].y + v2 * arv[n].z + v3 * arv[n].w;
                pk[n] = (u64)f2bf(v0) | ((u64)f2bf(v1) << 16) |
                        ((u64)f2bf(v2) << 32) | ((u64)f2bf(v3) << 48);
            }
            if (node < N_NODES) {
                const size_t base = (size_t)node * HD + h * D_HEAD + lg * 4;
#pragma unroll
                for (int n = 0; n < 4; ++n)
                    *reinterpret_cast<u64*>(&emb_bf[base + n * 16]) = pk[n];
            }
            dl += __shfl_xor(dl, 16, 64); dr += __shfl_xor(dr, 16, 64);
            dl += __shfl_xor(dl, 32, 64); dr += __shfl_xor(dr, 32, 64);
            if (lg == 0 && node < N_NODES) {
                s_l[node * H_HEADS + h] = dl;
                s_r[node * H_HEADS + h] = dr;
            }
        }
    } else {
        const int c0 = wv * 64 + lg * 4;
        float4 rb[4];
#pragma unroll
        for (int n = 0; n < 4; ++n)
            rb[n] = *reinterpret_cast<const float4*>(&resb[c0 + n * 16]);
#pragma unroll
        for (int m = 0; m < 4; ++m) {
            const int node = row0 + m * 16 + lr;
            if (node < N_NODES) {
                const size_t base = (size_t)node * HD + c0;
#pragma unroll
                for (int n = 0; n < 4; ++n) {
                    const float v0 = acc[m][n][0] + rb[n].x;
                    const float v1 = acc[m][n][1] + rb[n].y;
                    const float v2 = acc[m][n][2] + rb[n].z;
                    const float v3 = acc[m][n][3] + rb[n].w;
                    const u64 pk = (u64)f2bf(v0) | ((u64)f2bf(v1) << 16) |
                                   ((u64)f2bf(v2) << 32) | ((u64)f2bf(v3) << 48);
                    *reinterpret_cast<u64*>(&res_bf[base + n * 16]) = pk;
                }
            }
        }
    }
}

// ---------------- CSR build ----------------
__global__ void k_hist(const int* __restrict__ col, int* __restrict__ counts) {
    int e = blockIdx.x * 256 + threadIdx.x;
    if (e < E_EDGES) atomicAdd(&counts[col[e]], 1);
}

__global__ void k_scan1(const int* __restrict__ counts, int* __restrict__ row_ptr,
                        int* __restrict__ partials) {
    __shared__ int sd[256];
    const int t = threadIdx.x, b = blockIdx.x;
    const int base = b * 1024 + t * 4;
    int v[4];
#pragma unroll
    for (int j = 0; j < 4; ++j) v[j] = (base + j < N_NODES) ? counts[base + j] : 0;
    const int s = v[0] + v[1] + v[2] + v[3];
    sd[t] = s;
    __syncthreads();
    for (int off = 1; off < 256; off <<= 1) {
        int y = (t >= off) ? sd[t - off] : 0;
        __syncthreads();
        sd[t] += y;
        __syncthreads();
    }
    int p = sd[t] - s;
#pragma unroll
    for (int j = 0; j < 4; ++j) {
        if (base + j < N_NODES) row_ptr[base + j] = p;
        p += v[j];
    }
    if (t == 255) partials[b] = sd[255];
}

__global__ void k_scan2(int* __restrict__ partials) {
    __shared__ int sd[128];
    const int t = threadIdx.x;
    const int v = (t < 98) ? partials[t] : 0;
    sd[t] = v;
    __syncthreads();
    for (int off = 1; off < 128; off <<= 1) {
        int y = (t >= off) ? sd[t - off] : 0;
        __syncthreads();
        sd[t] += y;
        __syncthreads();
    }
    if (t < 98) partials[t] = sd[t] - v;
}

__global__ void k_scan3(int* __restrict__ row_ptr, int* __restrict__ fill,
                        const int* __restrict__ partials) {
    const int i = blockIdx.x * 256 + threadIdx.x;
    if (i < N_NODES) {
        const int v = row_ptr[i] + partials[i >> 10];
        row_ptr[i] = v;
        fill[i] = v;
    }
    if (i == 0) row_ptr[N_NODES] = E_EDGES;
}

// ---------------- K4: scatter + per-edge attention exp, permuted outputs ----------------
__global__ void k_scatter(const int* __restrict__ row, const int* __restrict__ col,
                          const int* __restrict__ tp, const float* __restrict__ s_l,
                          const float* __restrict__ s_r, const float* __restrict__ s_e,
                          int* __restrict__ fill, int* __restrict__ perm_row,
                          float4* __restrict__ exw_perm) {
    const int e = blockIdx.x * 256 + threadIdx.x;
    if (e >= E_EDGES) return;
    const int r = row[e], c = col[e], t = tp[e];
    const float4 sl = *reinterpret_cast<const float4*>(&s_l[r * 4]);
    const float4 sr = *reinterpret_cast<const float4*>(&s_r[c * 4]);
    const float4 se = *reinterpret_cast<const float4*>(&s_e[t * 4]);
    float4 ex;
    float x;
    x = sl.x + sr.x + se.x; x = (x > 0.f) ? x : SLOPE * x; ex.x = __expf(x);
    x = sl.y + sr.y + se.y; x = (x > 0.f) ? x : SLOPE * x; ex.y = __expf(x);
    x = sl.z + sr.z + se.z; x = (x > 0.f) ? x : SLOPE * x; ex.z = __expf(x);
    x = sl.w + sr.w + se.w; x = (x > 0.f) ? x : SLOPE * x; ex.w = __expf(x);
    const int p = atomicAdd(&fill[c], 1);
    perm_row[p] = r;
    exw_perm[p] = ex;
}

// ---------------- K5: per-destination aggregation (one wave per node, 4-wide) -------------
__global__ __launch_bounds__(256)
void k_aggregate(const int* __restrict__ row_ptr, const int* __restrict__ perm_row,
                 const float* __restrict__ exw_perm,
                 const u16* __restrict__ emb_bf, const u16* __restrict__ res_bf,
                 float* __restrict__ outp) {
    const int wave = threadIdx.x >> 6;
    const int lane = threadIdx.x & 63;
    const int n = blockIdx.x * 4 + wave;           // grid = N/4 exactly
    const int h = lane >> 4;                       // this lane's head
    const int start = row_ptr[n], end = row_ptr[n + 1];
    const size_t o = (size_t)n * HD + lane * 4;
    const u64 rv = *reinterpret_cast<const u64*>(&res_bf[o]);

    float a0 = 0.f, a1 = 0.f, a2 = 0.f, a3 = 0.f, den = 0.f;
    int i = start;
    for (; i + 4 <= end; i += 4) {
        const int r0 = perm_row[i],     r1 = perm_row[i + 1];
        const int r2 = perm_row[i + 2], r3 = perm_row[i + 3];
        const float ex0 = exw_perm[(i)     * 4 + h];
        const float ex1 = exw_perm[(i + 1) * 4 + h];
        const float ex2 = exw_perm[(i + 2) * 4 + h];
        const float ex3 = exw_perm[(i + 3) * 4 + h];
        const u64 ev0 = *reinterpret_cast<const u64*>(&emb_bf[(size_t)r0 * HD + lane * 4]);
        const u64 ev1 = *reinterpret_cast<const u64*>(&emb_bf[(size_t)r1 * HD + lane * 4]);
        const u64 ev2 = *reinterpret_cast<const u64*>(&emb_bf[(size_t)r2 * HD + lane * 4]);
        const u64 ev3 = *reinterpret_cast<const u64*>(&emb_bf[(size_t)r3 * HD + lane * 4]);
        a0 += ex0 * bf2f((unsigned)(ev0) & 0xFFFFu)       + ex1 * bf2f((unsigned)(ev1) & 0xFFFFu)
            + ex2 * bf2f((unsigned)(ev2) & 0xFFFFu)       + ex3 * bf2f((unsigned)(ev3) & 0xFFFFu);
        a1 += ex0 * bf2f((unsigned)(ev0 >> 16) & 0xFFFFu) + ex1 * bf2f((unsigned)(ev1 >> 16) & 0xFFFFu)
            + ex2 * bf2f((unsigned)(ev2 >> 16) & 0xFFFFu) + ex3 * bf2f((unsigned)(ev3 >> 16) & 0xFFFFu);
        a2 += ex0 * bf2f((unsigned)(ev0 >> 32) & 0xFFFFu) + ex1 * bf2f((unsigned)(ev1 >> 32) & 0xFFFFu)
            + ex2 * bf2f((unsigned)(ev2 >> 32) & 0xFFFFu) + ex3 * bf2f((unsigned)(ev3 >> 32) & 0xFFFFu);
        a3 += ex0 * bf2f((unsigned)(ev0 >> 48) & 0xFFFFu) + ex1 * bf2f((unsigned)(ev1 >> 48) & 0xFFFFu)
            + ex2 * bf2f((unsigned)(ev2 >> 48) & 0xFFFFu) + ex3 * bf2f((unsigned)(ev3 >> 48) & 0xFFFFu);
        den += ex0 + ex1 + ex2 + ex3;
    }
    for (; i < end; ++i) {
        const int r0 = perm_row[i];
        const float ex0 = exw_perm[i * 4 + h];
        const u64 ev0 = *reinterpret_cast<const u64*>(&emb_bf[(size_t)r0 * HD + lane * 4]);
        a0 += ex0 * bf2f((unsigned)(ev0) & 0xFFFFu);
        a1 += ex0 * bf2f((unsigned)(ev0 >> 16) & 0xFFFFu);
        a2 += ex0 * bf2f((unsigned)(ev0 >> 32) & 0xFFFFu);
        a3 += ex0 * bf2f((unsigned)(ev0 >> 48) & 0xFFFFu);
        den += ex0;
    }
    const float inv = (den > 0.f) ? 1.f / den : 0.f;
    float4 out;
    float x;
    x = a0 * inv + bf2f((unsigned)(rv) & 0xFFFFu);       out.x = (x > 0.f) ? x : __expf(x) - 1.f;
    x = a1 * inv + bf2f((unsigned)(rv >> 16) & 0xFFFFu); out.y = (x > 0.f) ? x : __expf(x) - 1.f;
    x = a2 * inv + bf2f((unsigned)(rv >> 32) & 0xFFFFu); out.z = (x > 0.f) ? x : __expf(x) - 1.f;
    x = a3 * inv + bf2f((unsigned)(rv >> 48) & 0xFFFFu); out.w = (x > 0.f) ? x : __expf(x) - 1.f;
    *reinterpret_cast<float4*>(&outp[o]) = out;
}

extern "C" void kernel_launch(void* const* d_in, const int* in_sizes, int n_in,
                              void* d_out, int out_size, void* d_ws, size_t ws_size,
                              hipStream_t stream) {
    const float* h    = (const float*)d_in[0];
    const float* W    = (const float*)d_in[1];
    const float* W_e  = (const float*)d_in[2];
    const float* eemb = (const float*)d_in[3];
    const float* a_l  = (const float*)d_in[4];
    const float* a_r  = (const float*)d_in[5];
    const float* a_e  = (const float*)d_in[6];
    const float* resW = (const float*)d_in[7];
    const float* resb = (const float*)d_in[8];
    const int* row = (const int*)d_in[9];
    const int* col = (const int*)d_in[10];
    const int* tp  = (const int*)d_in[11];
    float* outp = (float*)d_out;

    char* ws = (char*)d_ws;
    size_t off = 0;
    auto alloc = [&](size_t b) { size_t o = off; off += (b + 255) & ~(size_t)255; return o; };
    u16*  Bfrag   = (u16*)(ws + alloc((size_t)512 * IN_F * 2));
    u16*  emb_bf  = (u16*)(ws + alloc((size_t)N_NODES * HD * 2));
    u16*  res_bf  = (u16*)(ws + alloc((size_t)N_NODES * HD * 2));
    float* s_l    = (float*)(ws + alloc((size_t)N_NODES * H_HEADS * 4));
    float* s_r    = (float*)(ws + alloc((size_t)N_NODES * H_HEADS * 4));
    float* s_e    = (float*)(ws + alloc(NET_T * H_HEADS * 4));
    int*  counts  = (int*)(ws + alloc((size_t)N_NODES * 4));
    int*  row_ptr = (int*)(ws + alloc((size_t)(N_NODES + 1) * 4));
    int*  fill    = (int*)(ws + alloc((size_t)N_NODES * 4));
    int*  perm_row= (int*)(ws + alloc((size_t)E_EDGES * 4));
    float* exw_perm=(float*)(ws + alloc((size_t)E_EDGES * H_HEADS * 4));
    int*  partials= (int*)(ws + alloc(128 * 4));

    k_se<<<1, 256, 0, stream>>>(eemb, W_e, a_e, s_e);
    k_prep_w<<<64, 256, 0, stream>>>(W, resW, Bfrag);
    dim3 g2(NTILES, 2);
    k_mfma<<<g2, 256, 0, stream>>>(h, Bfrag, a_l, a_r, resb, emb_bf, s_l, s_r, res_bf);
    hipMemsetAsync(counts, 0, (size_t)N_NODES * 4, stream);
    k_hist<<<(E_EDGES + 255) / 256, 256, 0, stream>>>(col, counts);
    k_scan1<<<98, 256, 0, stream>>>(counts, row_ptr, partials);
    k_scan2<<<1, 128, 0, stream>>>(partials);
    k_scan3<<<(N_NODES + 255) / 256, 256, 0, stream>>>(row_ptr, fill, partials);
    k_scatter<<<(E_EDGES + 255) / 256, 256, 0, stream>>>(row, col, tp, s_l, s_r, s_e,
                                                         fill, perm_row, (float4*)exw_perm);
    k_aggregate<<<N_NODES / 4, 256, 0, stream>>>(row_ptr, perm_row, exw_perm, emb_bf, res_bf, outp);
}

// Round 9
// 296.605 us; speedup vs baseline: 1.2336x; 1.0408x over previous
//
#include <hip/hip_runtime.h>

#define N_NODES 100000
#define E_EDGES 800000
#define IN_F 256
#define D_HEAD 64
#define H_HEADS 4
#define EF_F 64
#define NET_T 8
#define HD 256          // H*D
#define SLOPE 0.2f
#define NTILES ((N_NODES + 63) / 64)

typedef unsigned short u16;
typedef unsigned long long u64;
typedef __attribute__((ext_vector_type(8))) short bf16x8;
typedef __attribute__((ext_vector_type(4))) float f32x4;

static __device__ __forceinline__ u16 f2bf(float f) {
    unsigned int u = __float_as_uint(f);
    unsigned int r = u + 0x7FFFu + ((u >> 16) & 1u);
    return (u16)(r >> 16);
}
static __device__ __forceinline__ float bf2f(unsigned int u) {
    return __uint_as_float(u << 16);
}

// ---------------- K0: s_e[t][h] = sum_f a_e[h,f] * (edge_emb @ W_e)[t,h,f] ----------------
__global__ void k_se(const float* __restrict__ edge_emb, const float* __restrict__ W_e,
                     const float* __restrict__ a_e, float* __restrict__ s_e) {
    int tid = threadIdx.x;           // 256 threads
    int t  = tid >> 5;               // 0..7
    int h  = (tid >> 3) & 3;         // 0..3
    int fc = tid & 7;                // 0..7
    float part = 0.f;
    for (int j = 0; j < 8; ++j) {
        int f = fc * 8 + j;
        float acc = 0.f;
        for (int k = 0; k < EF_F; ++k)
            acc += edge_emb[t * EF_F + k] * W_e[k * (EF_F * H_HEADS) + h * EF_F + f];
        part += a_e[h * EF_F + f] * acc;
    }
    for (int off = 1; off < 8; off <<= 1)
        part += __shfl_xor(part, off, 64);
    if (fc == 0) s_e[t * H_HEADS + h] = part;
}

// ---------------- K1: Bfrag[g][ks][n][lane] fragment-major bf16 of [W | res_W]^T ----------
__global__ void k_prep_w(const float* __restrict__ W, const float* __restrict__ resW,
                         u16* __restrict__ Bfrag) {
    const int gid = blockIdx.x * 256 + threadIdx.x;   // 16384 total
    const int lane = gid & 63;
    const int fragid = gid >> 6;          // 0..255 = g*32 + ks*4 + n
    const int n = fragid & 3;
    const int ks = (fragid >> 2) & 7;
    const int g = fragid >> 5;            // 0..7
    const int c = g * 64 + n * 16 + (lane & 15);      // 0..511
    const int k0 = ks * 32 + (lane >> 4) * 8;
    const float* src = (c < HD) ? &W[c] : &resW[c - HD];
    u16 tmp[8];
#pragma unroll
    for (int j = 0; j < 8; ++j)
        tmp[j] = f2bf(src[(size_t)(k0 + j) * HD]);
    *reinterpret_cast<uint4*>(&Bfrag[(size_t)fragid * 512 + lane * 8]) =
        *reinterpret_cast<const uint4*>(tmp);
}

// ---------------- K2: fused convert + MFMA GEMM (4-wave blocks, pair-adjacent tiles) ------
// 1D grid 2*NTILES: tile = bid>>1, by = bid&1. The two blocks of a tile are
// dispatch-adjacent so the second one's A-tile reads hit L2/L3 (single HBM fetch).
// by=0: emb heads (wave = head); by=1: residual (bf16 store to res_bf).
__global__ __launch_bounds__(256, 4)
void k_mfma(const float* __restrict__ A, const u16* __restrict__ Bfrag,
            const float* __restrict__ a_l, const float* __restrict__ a_r,
            const float* __restrict__ resb,
            u16* __restrict__ emb_bf, float* __restrict__ s_l, float* __restrict__ s_r,
            u16* __restrict__ res_bf) {
    __shared__ char At[32768];       // 64 rows x 256 bf16, XOR-swizzled
    const int tid = threadIdx.x;
    const int lane = tid & 63;
    const int wv = tid >> 6;         // 0..3
    const int by = blockIdx.x & 1;   // 0: emb, 1: residual
    const int wid = (by << 2) | wv;  // global channel-group 0..7
    const int row0 = (blockIdx.x >> 1) * 64;

    // ---- stage: 16 iters x 256 thr x 8B(bf16); fp32 read 16B/thread ----
#pragma unroll
    for (int c = 0; c < 16; ++c) {
        const int lin8 = c * 2048 + tid * 8;          // linear byte in bf16 tile
        const int r_lin = lin8 >> 9;                  // tile row 0..63
        int grow = row0 + r_lin;
        if (grow >= N_NODES) grow = N_NODES - 1;      // clamp (stores masked later)
        const int colb = lin8 & 511;
        const float4 v = *reinterpret_cast<const float4*>(&A[(size_t)grow * IN_F + (colb >> 1)]);
        uint2 o;
        o.x = (unsigned)f2bf(v.x) | ((unsigned)f2bf(v.y) << 16);
        o.y = (unsigned)f2bf(v.z) | ((unsigned)f2bf(v.w) << 16);
        *reinterpret_cast<uint2*>(&At[lin8 ^ ((r_lin & 7) << 4)]) = o;
    }
    __syncthreads();

    const int lr = lane & 15;
    const int lg = lane >> 4;
    const int xr = (lr & 7) << 4;                     // swizzle term
    const int klg = lg * 16;                          // byte k-chunk offset in row

    int rowbase[4];
#pragma unroll
    for (int m = 0; m < 4; ++m) rowbase[m] = (m * 16 + lr) * 512;

    const u16* bp = Bfrag + (size_t)wid * 16384 + lane * 8;

    f32x4 acc[4][4] = {};
#pragma unroll
    for (int ks = 0; ks < 8; ++ks) {
        bf16x8 af[4], bfr[4];
        const int kx = ((ks << 6) + klg) ^ xr;        // swizzled intra-row byte
#pragma unroll
        for (int n = 0; n < 4; ++n)
            bfr[n] = *reinterpret_cast<const bf16x8*>(&bp[ks * 2048 + n * 512]);
#pragma unroll
        for (int m = 0; m < 4; ++m)
            af[m] = *reinterpret_cast<const bf16x8*>(&At[rowbase[m] + kx]);
#pragma unroll
        for (int m = 0; m < 4; ++m)
#pragma unroll
            for (int n = 0; n < 4; ++n)
                acc[m][n] = __builtin_amdgcn_mfma_f32_16x16x32_bf16(bfr[n], af[m], acc[m][n], 0, 0, 0);
    }
    // acc[m][n][r]: node=row0+m*16+lr, channel (within group) n*16+lg*4+r

    if (by == 0) {
        const int h = wv;
        float4 alv[4], arv[4];
#pragma unroll
        for (int n = 0; n < 4; ++n) {
            alv[n] = *reinterpret_cast<const float4*>(&a_l[h * D_HEAD + n * 16 + lg * 4]);
            arv[n] = *reinterpret_cast<const float4*>(&a_r[h * D_HEAD + n * 16 + lg * 4]);
        }
#pragma unroll
        for (int m = 0; m < 4; ++m) {
            const int node = row0 + m * 16 + lr;
            float dl = 0.f, dr = 0.f;
            u64 pk[4];
#pragma unroll
            for (int n = 0; n < 4; ++n) {
                float v0 = acc[m][n][0], v1 = acc[m][n][1], v2 = acc[m][n][2], v3 = acc[m][n][3];
                v0 = isnan(v0) ? 0.f : v0;            // nan_to_num
                v1 = isnan(v1) ? 0.f : v1;
                v2 = isnan(v2) ? 0.f : v2;
                v3 = isnan(v3) ? 0.f : v3;
                dl += v0 * alv[n].x + v1 * alv[n].y + v2 * alv[n].z + v3 * alv[n].w;
                dr += v0 * arv[n].x + v1 * arv[n].y + v2 * arv[n].z + v3 * arv[n].w;
                pk[n] = (u64)f2bf(v0) | ((u64)f2bf(v1) << 16) |
                        ((u64)f2bf(v2) << 32) | ((u64)f2bf(v3) << 48);
            }
            if (node < N_NODES) {
                const size_t base = (size_t)node * HD + h * D_HEAD + lg * 4;
#pragma unroll
                for (int n = 0; n < 4; ++n)
                    *reinterpret_cast<u64*>(&emb_bf[base + n * 16]) = pk[n];
            }
            dl += __shfl_xor(dl, 16, 64); dr += __shfl_xor(dr, 16, 64);
            dl += __shfl_xor(dl, 32, 64); dr += __shfl_xor(dr, 32, 64);
            if (lg == 0 && node < N_NODES) {
                s_l[node * H_HEADS + h] = dl;
                s_r[node * H_HEADS + h] = dr;
            }
        }
    } else {
        const int c0 = wv * 64 + lg * 4;
        float4 rb[4];
#pragma unroll
        for (int n = 0; n < 4; ++n)
            rb[n] = *reinterpret_cast<const float4*>(&resb[c0 + n * 16]);
#pragma unroll
        for (int m = 0; m < 4; ++m) {
            const int node = row0 + m * 16 + lr;
            if (node < N_NODES) {
                const size_t base = (size_t)node * HD + c0;
#pragma unroll
                for (int n = 0; n < 4; ++n) {
                    const float v0 = acc[m][n][0] + rb[n].x;
                    const float v1 = acc[m][n][1] + rb[n].y;
                    const float v2 = acc[m][n][2] + rb[n].z;
                    const float v3 = acc[m][n][3] + rb[n].w;
                    const u64 pk = (u64)f2bf(v0) | ((u64)f2bf(v1) << 16) |
                                   ((u64)f2bf(v2) << 32) | ((u64)f2bf(v3) << 48);
                    *reinterpret_cast<u64*>(&res_bf[base + n * 16]) = pk;
                }
            }
        }
    }
}

// ---------------- CSR build ----------------
__global__ void k_hist(const int* __restrict__ col, int* __restrict__ counts) {
    int e = blockIdx.x * 256 + threadIdx.x;
    if (e < E_EDGES) atomicAdd(&counts[col[e]], 1);
}

__global__ void k_scan1(const int* __restrict__ counts, int* __restrict__ row_ptr,
                        int* __restrict__ partials) {
    __shared__ int sd[256];
    const int t = threadIdx.x, b = blockIdx.x;
    const int base = b * 1024 + t * 4;
    int v[4];
#pragma unroll
    for (int j = 0; j < 4; ++j) v[j] = (base + j < N_NODES) ? counts[base + j] : 0;
    const int s = v[0] + v[1] + v[2] + v[3];
    sd[t] = s;
    __syncthreads();
    for (int off = 1; off < 256; off <<= 1) {
        int y = (t >= off) ? sd[t - off] : 0;
        __syncthreads();
        sd[t] += y;
        __syncthreads();
    }
    int p = sd[t] - s;
#pragma unroll
    for (int j = 0; j < 4; ++j) {
        if (base + j < N_NODES) row_ptr[base + j] = p;
        p += v[j];
    }
    if (t == 255) partials[b] = sd[255];
}

__global__ void k_scan2(int* __restrict__ partials) {
    __shared__ int sd[128];
    const int t = threadIdx.x;
    const int v = (t < 98) ? partials[t] : 0;
    sd[t] = v;
    __syncthreads();
    for (int off = 1; off < 128; off <<= 1) {
        int y = (t >= off) ? sd[t - off] : 0;
        __syncthreads();
        sd[t] += y;
        __syncthreads();
    }
    if (t < 98) partials[t] = sd[t] - v;
}

__global__ void k_scan3(int* __restrict__ row_ptr, int* __restrict__ fill,
                        const int* __restrict__ partials) {
    const int i = blockIdx.x * 256 + threadIdx.x;
    if (i < N_NODES) {
        const int v = row_ptr[i] + partials[i >> 10];
        row_ptr[i] = v;
        fill[i] = v;
    }
    if (i == 0) row_ptr[N_NODES] = E_EDGES;
}

// ---------------- K4: scatter + per-edge attention exp, permuted outputs ----------------
__global__ void k_scatter(const int* __restrict__ row, const int* __restrict__ col,
                          const int* __restrict__ tp, const float* __restrict__ s_l,
                          const float* __restrict__ s_r, const float* __restrict__ s_e,
                          int* __restrict__ fill, int* __restrict__ perm_row,
                          float4* __restrict__ exw_perm) {
    const int e = blockIdx.x * 256 + threadIdx.x;
    if (e >= E_EDGES) return;
    const int r = row[e], c = col[e], t = tp[e];
    const float4 sl = *reinterpret_cast<const float4*>(&s_l[r * 4]);
    const float4 sr = *reinterpret_cast<const float4*>(&s_r[c * 4]);
    const float4 se = *reinterpret_cast<const float4*>(&s_e[t * 4]);
    float4 ex;
    float x;
    x = sl.x + sr.x + se.x; x = (x > 0.f) ? x : SLOPE * x; ex.x = __expf(x);
    x = sl.y + sr.y + se.y; x = (x > 0.f) ? x : SLOPE * x; ex.y = __expf(x);
    x = sl.z + sr.z + se.z; x = (x > 0.f) ? x : SLOPE * x; ex.z = __expf(x);
    x = sl.w + sr.w + se.w; x = (x > 0.f) ? x : SLOPE * x; ex.w = __expf(x);
    const int p = atomicAdd(&fill[c], 1);
    perm_row[p] = r;
    exw_perm[p] = ex;
}

// ---------------- K5: per-destination aggregation (one wave per node, 4-wide) -------------
__global__ __launch_bounds__(256)
void k_aggregate(const int* __restrict__ row_ptr, const int* __restrict__ perm_row,
                 const float* __restrict__ exw_perm,
                 const u16* __restrict__ emb_bf, const u16* __restrict__ res_bf,
                 float* __restrict__ outp) {
    const int wave = threadIdx.x >> 6;
    const int lane = threadIdx.x & 63;
    const int n = blockIdx.x * 4 + wave;           // grid = N/4 exactly
    const int h = lane >> 4;                       // this lane's head
    const int start = row_ptr[n], end = row_ptr[n + 1];
    const size_t o = (size_t)n * HD + lane * 4;
    const u64 rv = *reinterpret_cast<const u64*>(&res_bf[o]);

    float a0 = 0.f, a1 = 0.f, a2 = 0.f, a3 = 0.f, den = 0.f;
    int i = start;
    for (; i + 4 <= end; i += 4) {
        const int r0 = perm_row[i],     r1 = perm_row[i + 1];
        const int r2 = perm_row[i + 2], r3 = perm_row[i + 3];
        const float ex0 = exw_perm[(i)     * 4 + h];
        const float ex1 = exw_perm[(i + 1) * 4 + h];
        const float ex2 = exw_perm[(i + 2) * 4 + h];
        const float ex3 = exw_perm[(i + 3) * 4 + h];
        const u64 ev0 = *reinterpret_cast<const u64*>(&emb_bf[(size_t)r0 * HD + lane * 4]);
        const u64 ev1 = *reinterpret_cast<const u64*>(&emb_bf[(size_t)r1 * HD + lane * 4]);
        const u64 ev2 = *reinterpret_cast<const u64*>(&emb_bf[(size_t)r2 * HD + lane * 4]);
        const u64 ev3 = *reinterpret_cast<const u64*>(&emb_bf[(size_t)r3 * HD + lane * 4]);
        const unsigned l0 = (unsigned)ev0, h0 = (unsigned)(ev0 >> 32);
        const unsigned l1 = (unsigned)ev1, h1 = (unsigned)(ev1 >> 32);
        const unsigned l2 = (unsigned)ev2, h2 = (unsigned)(ev2 >> 32);
        const unsigned l3 = (unsigned)ev3, h3 = (unsigned)(ev3 >> 32);
        a0 += ex0 * __uint_as_float(l0 << 16)          + ex1 * __uint_as_float(l1 << 16)
            + ex2 * __uint_as_float(l2 << 16)          + ex3 * __uint_as_float(l3 << 16);
        a1 += ex0 * __uint_as_float(l0 & 0xFFFF0000u)  + ex1 * __uint_as_float(l1 & 0xFFFF0000u)
            + ex2 * __uint_as_float(l2 & 0xFFFF0000u)  + ex3 * __uint_as_float(l3 & 0xFFFF0000u);
        a2 += ex0 * __uint_as_float(h0 << 16)          + ex1 * __uint_as_float(h1 << 16)
            + ex2 * __uint_as_float(h2 << 16)          + ex3 * __uint_as_float(h3 << 16);
        a3 += ex0 * __uint_as_float(h0 & 0xFFFF0000u)  + ex1 * __uint_as_float(h1 & 0xFFFF0000u)
            + ex2 * __uint_as_float(h2 & 0xFFFF0000u)  + ex3 * __uint_as_float(h3 & 0xFFFF0000u);
        den += ex0 + ex1 + ex2 + ex3;
    }
    for (; i < end; ++i) {
        const int r0 = perm_row[i];
        const float ex0 = exw_perm[i * 4 + h];
        const u64 ev0 = *reinterpret_cast<const u64*>(&emb_bf[(size_t)r0 * HD + lane * 4]);
        const unsigned l0 = (unsigned)ev0, h0 = (unsigned)(ev0 >> 32);
        a0 += ex0 * __uint_as_float(l0 << 16);
        a1 += ex0 * __uint_as_float(l0 & 0xFFFF0000u);
        a2 += ex0 * __uint_as_float(h0 << 16);
        a3 += ex0 * __uint_as_float(h0 & 0xFFFF0000u);
        den += ex0;
    }
    const float inv = (den > 0.f) ? 1.f / den : 0.f;
    f32x4 out;
    float x;
    x = a0 * inv + bf2f((unsigned)(rv) & 0xFFFFu);       out.x = (x > 0.f) ? x : __expf(x) - 1.f;
    x = a1 * inv + bf2f((unsigned)(rv >> 16) & 0xFFFFu); out.y = (x > 0.f) ? x : __expf(x) - 1.f;
    x = a2 * inv + bf2f((unsigned)(rv >> 32) & 0xFFFFu); out.z = (x > 0.f) ? x : __expf(x) - 1.f;
    x = a3 * inv + bf2f((unsigned)(rv >> 48) & 0xFFFFu); out.w = (x > 0.f) ? x : __expf(x) - 1.f;
    __builtin_nontemporal_store(out, reinterpret_cast<f32x4*>(&outp[o]));
}

extern "C" void kernel_launch(void* const* d_in, const int* in_sizes, int n_in,
                              void* d_out, int out_size, void* d_ws, size_t ws_size,
                              hipStream_t stream) {
    const float* h    = (const float*)d_in[0];
    const float* W    = (const float*)d_in[1];
    const float* W_e  = (const float*)d_in[2];
    const float* eemb = (const float*)d_in[3];
    const float* a_l  = (const float*)d_in[4];
    const float* a_r  = (const float*)d_in[5];
    const float* a_e  = (const float*)d_in[6];
    const float* resW = (const float*)d_in[7];
    const float* resb = (const float*)d_in[8];
    const int* row = (const int*)d_in[9];
    const int* col = (const int*)d_in[10];
    const int* tp  = (const int*)d_in[11];
    float* outp = (float*)d_out;

    char* ws = (char*)d_ws;
    size_t off = 0;
    auto alloc = [&](size_t b) { size_t o = off; off += (b + 255) & ~(size_t)255; return o; };
    u16*  Bfrag   = (u16*)(ws + alloc((size_t)512 * IN_F * 2));
    u16*  emb_bf  = (u16*)(ws + alloc((size_t)N_NODES * HD * 2));
    u16*  res_bf  = (u16*)(ws + alloc((size_t)N_NODES * HD * 2));
    float* s_l    = (float*)(ws + alloc((size_t)N_NODES * H_HEADS * 4));
    float* s_r    = (float*)(ws + alloc((size_t)N_NODES * H_HEADS * 4));
    float* s_e    = (float*)(ws + alloc(NET_T * H_HEADS * 4));
    int*  counts  = (int*)(ws + alloc((size_t)N_NODES * 4));
    int*  row_ptr = (int*)(ws + alloc((size_t)(N_NODES + 1) * 4));
    int*  fill    = (int*)(ws + alloc((size_t)N_NODES * 4));
    int*  perm_row= (int*)(ws + alloc((size_t)E_EDGES * 4));
    float* exw_perm=(float*)(ws + alloc((size_t)E_EDGES * H_HEADS * 4));
    int*  partials= (int*)(ws + alloc(128 * 4));

    k_se<<<1, 256, 0, stream>>>(eemb, W_e, a_e, s_e);
    k_prep_w<<<64, 256, 0, stream>>>(W, resW, Bfrag);
    k_mfma<<<NTILES * 2, 256, 0, stream>>>(h, Bfrag, a_l, a_r, resb, emb_bf, s_l, s_r, res_bf);
    (void)hipMemsetAsync(counts, 0, (size_t)N_NODES * 4, stream);
    k_hist<<<(E_EDGES + 255) / 256, 256, 0, stream>>>(col, counts);
    k_scan1<<<98, 256, 0, stream>>>(counts, row_ptr, partials);
    k_scan2<<<1, 128, 0, stream>>>(partials);
    k_scan3<<<(N_NODES + 255) / 256, 256, 0, stream>>>(row_ptr, fill, partials);
    k_scatter<<<(E_EDGES + 255) / 256, 256, 0, stream>>>(row, col, tp, s_l, s_r, s_e,
                                                         fill, perm_row, (float4*)exw_perm);
    k_aggregate<<<N_NODES / 4, 256, 0, stream>>>(row_ptr, perm_row, exw_perm, emb_bf, res_bf, outp);
}